// Round 1
// baseline (99.396 us; speedup 1.0000x reference)
//
#include <hip/hip_runtime.h>
#include <math.h>

#define MARGIN 1.0f

typedef short short8 __attribute__((ext_vector_type(8)));
typedef unsigned short ushort8 __attribute__((ext_vector_type(8)));
typedef float floatx16 __attribute__((ext_vector_type(16)));

typedef const __attribute__((address_space(1))) void g_void;
typedef __attribute__((address_space(3))) void s_void;

__device__ inline unsigned short bf16_rne(float x) {
  unsigned u = __float_as_uint(x);
  unsigned r = (u + 0x7FFF + ((u >> 16) & 1)) >> 16;
  return (unsigned short)r;
}
__device__ inline float bf16_to_f32(unsigned short h) {
  return __uint_as_float(((unsigned)h) << 16);
}

// ---------------- Kernel A: fp32 -> bf16 hi/lo split (CHUNKED layout) -------
// New structure: 16 blocks x 1024 threads. lane = row-within-band, so for a
// fixed chunk the 64 lanes of a wave write 64 consecutive rows = 1 KB
// contiguous ushort8 stores (old version: 16 B scattered at 16 KB stride,
// partial-line HBM writes). Each thread owns 4 chunks of its row; sq is
// reduced across the 16 chunk-groups via LDS. Also zeroes the completion
// counter used by the fused anchor+final kernel.
__global__ __launch_bounds__(1024) void conv_kernel(
    const float* __restrict__ f, unsigned short* __restrict__ fhi,
    unsigned short* __restrict__ flo, float* __restrict__ sq,
    int* __restrict__ counter, int N, int D) {
  const int t = threadIdx.x;
  const int lane = t & 63;
  const int cg = t >> 6;                 // chunk-group 0..15
  const int row = blockIdx.x * 64 + lane;

  if (blockIdx.x == 0 && t == 0) *counter = 0;   // for anchor kernel's last-block pattern

  float partial = 0.f;
#pragma unroll
  for (int ci = 0; ci < 4; ++ci) {
    const int c = cg * 4 + ci;           // chunk 0..63 (D/8 = 64)
    if (c * 8 >= D) break;
    const float* src = f + (size_t)row * D + c * 8;
    float4 v0 = *(const float4*)(src);
    float4 v1 = *(const float4*)(src + 4);
    float xs[8] = {v0.x, v0.y, v0.z, v0.w, v1.x, v1.y, v1.z, v1.w};
    ushort8 hs, ls;
#pragma unroll
    for (int e = 0; e < 8; ++e) {
      float x = xs[e];
      partial += x * x;
      unsigned short hh = bf16_rne(x);
      hs[e] = hh;
      ls[e] = bf16_rne(x - bf16_to_f32(hh));
    }
    const size_t off = ((size_t)c * N + row) * 8;   // [chunk][row][8]
    *(ushort8*)(fhi + off) = hs;                    // coalesced: lanes -> rows
    *(ushort8*)(flo + off) = ls;
  }

  __shared__ float sred[16][64];
  sred[cg][lane] = partial;
  __syncthreads();
  if (cg == 0) {
    float s = 0.f;
#pragma unroll
    for (int w2 = 0; w2 < 16; ++w2) s += sred[w2][lane];
    sq[row] = s;
  }
}

// ---------------- Kernel B: distance matrix via bf16 MFMA hi/lo -------------
// 64x64 tile per block, 4 waves, one 32x32 MFMA tile each. global_load_lds
// staging (16B/lane direct-to-LDS), double-buffered. CHANGE vs prev round:
// the 12 MFMAs per K-step were one serial dependency chain through a single
// accumulator (fully latency-exposed at 1 wave/SIMD). Now 3 independent
// chains (ah*bh, ah*bl, al*bh) summed in the epilogue -> 3x issue ILP.
__global__ __launch_bounds__(256) void dist_kernel(
    const unsigned short* __restrict__ fhi, const unsigned short* __restrict__ flo,
    const float* __restrict__ sqv, float* __restrict__ dist, int N, int D) {
  // [2 bufs][4 arrays: Ah,Al,Bh,Bl][8 chunks][64 rows] of ushort8 = 64 KB
  __shared__ ushort8 T[2][4][8][64];

  const int tid = threadIdx.x;
  const int w = tid >> 6;          // wave 0..3
  const int lane = tid & 63;
  const int rowBase = blockIdx.y * 64;
  const int colBase = blockIdx.x * 64;

  const unsigned short* srcs[4] = {fhi, flo, fhi, flo};
  const int bases[4] = {rowBase, rowBase, colBase, colBase};

  const int wr = (w >> 1) * 32;
  const int wc = (w & 1) * 32;
  const int m = lane & 31;
  const int h = lane >> 5;         // k-half selector

  auto issueLoads = [&](int k0, int bb) {
    const int c0 = k0 >> 3;
#pragma unroll
    for (int s = 0; s < 8; ++s) {
      const int a = s >> 1;
      const int c = (w << 1) | (s & 1);
      const unsigned short* gp =
          srcs[a] + ((size_t)(c0 + c) * N + bases[a] + lane) * 8;
      __builtin_amdgcn_global_load_lds((g_void*)gp, (s_void*)&T[bb][a][c][0],
                                       16, 0, 0);
    }
  };

  floatx16 acc0 = {}, acc1 = {}, acc2 = {};
  int b = 0;

  issueLoads(0, 0);
  __syncthreads();   // vmcnt(0) drained -> buf0 visible

  for (int k0 = 0; k0 < D; k0 += 64) {
    if (k0 + 64 < D) issueLoads(k0 + 64, b ^ 1);   // async into other buffer
#pragma unroll
    for (int kk = 0; kk < 4; ++kk) {
      const int c = 2 * kk + h;
      short8 ahf = *(const short8*)&T[b][0][c][wr + m];
      short8 alf = *(const short8*)&T[b][1][c][wr + m];
      short8 bhf = *(const short8*)&T[b][2][c][wc + m];
      short8 blf = *(const short8*)&T[b][3][c][wc + m];
      acc0 = __builtin_amdgcn_mfma_f32_32x32x16_bf16(ahf, bhf, acc0, 0, 0, 0);
      acc1 = __builtin_amdgcn_mfma_f32_32x32x16_bf16(ahf, blf, acc1, 0, 0, 0);
      acc2 = __builtin_amdgcn_mfma_f32_32x32x16_bf16(alf, bhf, acc2, 0, 0, 0);
    }
    __syncthreads();   // drains prefetch DMA + all waves' LDS reads of buf b
    b ^= 1;
  }

  // Epilogue: C/D layout col=lane&31, row=(reg&3)+8*(reg>>2)+4*(lane>>5)
  const int col = colBase + wc + m;
  const float sqc = sqv[col];
#pragma unroll
  for (int r = 0; r < 16; ++r) {
    const int row = rowBase + wr + (r & 3) + 8 * (r >> 2) + 4 * h;
    float a = acc0[r] + acc1[r] + acc2[r];
    float d2 = sqv[row] + sqc - 2.0f * a;
    d2 = d2 > 0.f ? d2 : 0.f;
    dist[(size_t)row * N + col] = sqrtf(d2);
  }
}

// ---------------- Kernel C: per-anchor loss + fused final reduction --------
// Same ballot-compaction body as before; the standalone final_reduce kernel
// is folded in via the deterministic last-block pattern: every block writes
// partial[i], release-fences, increments the counter; the block that sees
// count == N-1 acquire-fences and reduces partial[] in the exact same order
// the old final_reduce_kernel used (bit-identical output, one fewer launch).
__global__ __launch_bounds__(256) void anchor_loss_kernel(
    const float* __restrict__ dist, const int* __restrict__ labels,
    int* __restrict__ counter, float* __restrict__ out,
    float* __restrict__ partial, int N) {
  const int i = blockIdx.x;
  const int tid = threadIdx.x;
  const int lane = tid & 63;

  __shared__ float dpos[1024];   // stored as d + MARGIN
  __shared__ float dneg[1024];
  __shared__ int cnt[2];
  __shared__ float red[4];
  __shared__ int isLastS;

  if (tid < 2) cnt[tid] = 0;
  __syncthreads();

  const int lab = labels[i];
  const float* drow = dist + (size_t)i * N;

  for (int jb = 0; jb < N; jb += 256) {
    int j = jb + tid;
    float d = drow[j];
    bool isPos = (labels[j] == lab);

    unsigned long long mp = __ballot(isPos);
    unsigned long long mn = ~mp;   // all 64 lanes valid (N % 256 == 0)
    unsigned long long lt = (1ull << lane) - 1ull;

    int base_p = 0, base_n = 0;
    if (lane == 0) {
      base_p = atomicAdd(&cnt[0], __popcll(mp));
      base_n = atomicAdd(&cnt[1], 64 - __popcll(mp));
    }
    base_p = __shfl(base_p, 0, 64);
    base_n = __shfl(base_n, 0, 64);

    if (isPos) dpos[base_p + __popcll(mp & lt)] = d + MARGIN;
    else       dneg[base_n + __popcll(mn & lt)] = d;
  }
  __syncthreads();

  const int np = cnt[0], nn = cnt[1];

  float dk[4];
#pragma unroll
  for (int e = 0; e < 4; ++e) {
    int k = tid + 256 * e;
    dk[e] = (k < nn) ? dneg[k] : 1e30f;   // pad -> relu term 0
  }

  float accv = 0.f;
  for (int p = 0; p < np; ++p) {
    float tpos = dpos[p];                 // broadcast LDS read
#pragma unroll
    for (int e = 0; e < 4; ++e) {
      float v = tpos - dk[e];
      accv += (v > 0.f) ? v : 0.f;
    }
  }

  for (int off = 32; off > 0; off >>= 1) accv += __shfl_down(accv, off, 64);
  if (lane == 0) red[tid >> 6] = accv;
  __syncthreads();

  if (tid == 0) {
    partial[i] = red[0] + red[1] + red[2] + red[3];
    __threadfence();                        // release: partial visible device-wide
    isLastS = (atomicAdd(counter, 1) == gridDim.x - 1);
  }
  __syncthreads();
  if (!isLastS) return;

  // last block: deterministic final reduction (fixed order, any winner)
  __threadfence();                          // acquire: invalidate stale L2 lines
  float acc = 0.f;
  for (int j = tid; j < N; j += 256) acc += partial[j];
  for (int off = 32; off > 0; off >>= 1) acc += __shfl_down(acc, off, 64);
  if (lane == 0) red[tid >> 6] = acc;       // safe: prior red reads done pre-barrier
  __syncthreads();
  if (tid == 0) {
    double s = (double)red[0] + (double)red[1] + (double)red[2] + (double)red[3];
    out[0] = (float)(s / ((double)N + 1e-8));
  }
}

extern "C" void kernel_launch(void* const* d_in, const int* in_sizes, int n_in,
                              void* d_out, int out_size, void* d_ws, size_t ws_size,
                              hipStream_t stream) {
  const float* f = (const float*)d_in[0];
  const int* labels = (const int*)d_in[1];
  int N = in_sizes[1];           // 1024
  int D = in_sizes[0] / N;       // 512
  float* out = (float*)d_out;

  // ws layout: fhi [N*D u16 chunked] | flo [N*D u16 chunked] | sq [N f32]
  //          | dist [N*N f32] | partial [N f32] | counter [1 i32]
  unsigned short* fhi = (unsigned short*)d_ws;
  unsigned short* flo = fhi + (size_t)N * D;
  float* sq = (float*)(flo + (size_t)N * D);
  float* dist = sq + N;
  float* partial = dist + (size_t)N * N;
  int* counter = (int*)(partial + N);

  conv_kernel<<<N / 64, 1024, 0, stream>>>(f, fhi, flo, sq, counter, N, D);
  dim3 grid(N / 64, N / 64);
  dist_kernel<<<grid, 256, 0, stream>>>(fhi, flo, sq, dist, N, D);
  anchor_loss_kernel<<<N, 256, 0, stream>>>(dist, labels, counter, out, partial, N);
}

// Round 2
// 96.536 us; speedup vs baseline: 1.0296x; 1.0296x over previous
//
#include <hip/hip_runtime.h>
#include <math.h>

#define MARGIN 1.0f

typedef short short8 __attribute__((ext_vector_type(8)));
typedef unsigned short ushort8 __attribute__((ext_vector_type(8)));
typedef float floatx16 __attribute__((ext_vector_type(16)));

typedef const __attribute__((address_space(1))) void g_void;
typedef __attribute__((address_space(3))) void s_void;

__device__ inline unsigned short bf16_rne(float x) {
  unsigned u = __float_as_uint(x);
  unsigned r = (u + 0x7FFF + ((u >> 16) & 1)) >> 16;
  return (unsigned short)r;
}
__device__ inline float bf16_to_f32(unsigned short h) {
  return __uint_as_float(((unsigned)h) << 16);
}

// ---------------- Kernel A: fp32 -> bf16 hi/lo split (CHUNKED layout) -------
// ROUND-0 structure restored: 1024 blocks x 64 threads (one wave per row) —
// full-machine parallelism. Round-1's 16x1024 layout ran on 16/256 CUs and
// regressed 21 us. Scattered 16B stores here are absorbed by L2/L3 (4 MB
// total, consumed immediately by dist_kernel). Also zeroes the completion
// counter used by the fused anchor+final kernel.
__global__ __launch_bounds__(64) void conv_kernel(
    const float* __restrict__ f, unsigned short* __restrict__ fhi,
    unsigned short* __restrict__ flo, float* __restrict__ sq,
    int* __restrict__ counter, int N, int D) {
  const int r = blockIdx.x;
  const int t = threadIdx.x;
  if (r == 0 && t == 0) *counter = 0;   // reset for anchor kernel's last-block pattern
  float acc = 0.f;
  if (t * 8 < D) {
    const float* src = f + (size_t)r * D + t * 8;
    float4 v0 = *(const float4*)(src);
    float4 v1 = *(const float4*)(src + 4);
    float xs[8] = {v0.x, v0.y, v0.z, v0.w, v1.x, v1.y, v1.z, v1.w};
    ushort8 hs, ls;
#pragma unroll
    for (int e = 0; e < 8; ++e) {
      float x = xs[e];
      acc += x * x;
      unsigned short h = bf16_rne(x);
      hs[e] = h;
      ls[e] = bf16_rne(x - bf16_to_f32(h));
    }
    const size_t off = ((size_t)t * N + r) * 8;   // [chunk][row][8]
    *(ushort8*)(fhi + off) = hs;
    *(ushort8*)(flo + off) = ls;
  }
  for (int off = 32; off > 0; off >>= 1) acc += __shfl_down(acc, off, 64);
  if (t == 0) sq[r] = acc;
}

// ---------------- Kernel B: distance matrix via bf16 MFMA hi/lo -------------
// 64x64 tile per block, 4 waves, one 32x32 MFMA tile each. global_load_lds
// staging (16B/lane direct-to-LDS), double-buffered. 3 independent MFMA
// accumulator chains (ah*bh, ah*bl, al*bh) summed in the epilogue -> issue
// ILP at 1 wave/SIMD occupancy (the 12-deep single-chain version was fully
// latency-exposed).
__global__ __launch_bounds__(256) void dist_kernel(
    const unsigned short* __restrict__ fhi, const unsigned short* __restrict__ flo,
    const float* __restrict__ sqv, float* __restrict__ dist, int N, int D) {
  // [2 bufs][4 arrays: Ah,Al,Bh,Bl][8 chunks][64 rows] of ushort8 = 64 KB
  __shared__ ushort8 T[2][4][8][64];

  const int tid = threadIdx.x;
  const int w = tid >> 6;          // wave 0..3
  const int lane = tid & 63;
  const int rowBase = blockIdx.y * 64;
  const int colBase = blockIdx.x * 64;

  const unsigned short* srcs[4] = {fhi, flo, fhi, flo};
  const int bases[4] = {rowBase, rowBase, colBase, colBase};

  const int wr = (w >> 1) * 32;
  const int wc = (w & 1) * 32;
  const int m = lane & 31;
  const int h = lane >> 5;         // k-half selector

  auto issueLoads = [&](int k0, int bb) {
    const int c0 = k0 >> 3;
#pragma unroll
    for (int s = 0; s < 8; ++s) {
      const int a = s >> 1;
      const int c = (w << 1) | (s & 1);
      const unsigned short* gp =
          srcs[a] + ((size_t)(c0 + c) * N + bases[a] + lane) * 8;
      __builtin_amdgcn_global_load_lds((g_void*)gp, (s_void*)&T[bb][a][c][0],
                                       16, 0, 0);
    }
  };

  floatx16 acc0 = {}, acc1 = {}, acc2 = {};
  int b = 0;

  issueLoads(0, 0);
  __syncthreads();   // vmcnt(0) drained -> buf0 visible

  for (int k0 = 0; k0 < D; k0 += 64) {
    if (k0 + 64 < D) issueLoads(k0 + 64, b ^ 1);   // async into other buffer
#pragma unroll
    for (int kk = 0; kk < 4; ++kk) {
      const int c = 2 * kk + h;
      short8 ahf = *(const short8*)&T[b][0][c][wr + m];
      short8 alf = *(const short8*)&T[b][1][c][wr + m];
      short8 bhf = *(const short8*)&T[b][2][c][wc + m];
      short8 blf = *(const short8*)&T[b][3][c][wc + m];
      acc0 = __builtin_amdgcn_mfma_f32_32x32x16_bf16(ahf, bhf, acc0, 0, 0, 0);
      acc1 = __builtin_amdgcn_mfma_f32_32x32x16_bf16(ahf, blf, acc1, 0, 0, 0);
      acc2 = __builtin_amdgcn_mfma_f32_32x32x16_bf16(alf, bhf, acc2, 0, 0, 0);
    }
    __syncthreads();   // drains prefetch DMA + all waves' LDS reads of buf b
    b ^= 1;
  }

  // Epilogue: C/D layout col=lane&31, row=(reg&3)+8*(reg>>2)+4*(lane>>5)
  const int col = colBase + wc + m;
  const float sqc = sqv[col];
#pragma unroll
  for (int r = 0; r < 16; ++r) {
    const int row = rowBase + wr + (r & 3) + 8 * (r >> 2) + 4 * h;
    float a = acc0[r] + acc1[r] + acc2[r];
    float d2 = sqv[row] + sqc - 2.0f * a;
    d2 = d2 > 0.f ? d2 : 0.f;
    dist[(size_t)row * N + col] = sqrtf(d2);
  }
}

// ---------------- Kernel C: per-anchor loss + fused final reduction --------
// Ballot-compaction body; the standalone final_reduce kernel is folded in
// via the deterministic last-block pattern: every block writes partial[i],
// release-fences, increments the counter; the block that sees count == N-1
// acquire-fences and reduces partial[] in the exact same order the old
// final_reduce_kernel used (bit-identical output, one fewer launch).
__global__ __launch_bounds__(256) void anchor_loss_kernel(
    const float* __restrict__ dist, const int* __restrict__ labels,
    int* __restrict__ counter, float* __restrict__ out,
    float* __restrict__ partial, int N) {
  const int i = blockIdx.x;
  const int tid = threadIdx.x;
  const int lane = tid & 63;

  __shared__ float dpos[1024];   // stored as d + MARGIN
  __shared__ float dneg[1024];
  __shared__ int cnt[2];
  __shared__ float red[4];
  __shared__ int isLastS;

  if (tid < 2) cnt[tid] = 0;
  __syncthreads();

  const int lab = labels[i];
  const float* drow = dist + (size_t)i * N;

  for (int jb = 0; jb < N; jb += 256) {
    int j = jb + tid;
    float d = drow[j];
    bool isPos = (labels[j] == lab);

    unsigned long long mp = __ballot(isPos);
    unsigned long long mn = ~mp;   // all 64 lanes valid (N % 256 == 0)
    unsigned long long lt = (1ull << lane) - 1ull;

    int base_p = 0, base_n = 0;
    if (lane == 0) {
      base_p = atomicAdd(&cnt[0], __popcll(mp));
      base_n = atomicAdd(&cnt[1], 64 - __popcll(mp));
    }
    base_p = __shfl(base_p, 0, 64);
    base_n = __shfl(base_n, 0, 64);

    if (isPos) dpos[base_p + __popcll(mp & lt)] = d + MARGIN;
    else       dneg[base_n + __popcll(mn & lt)] = d;
  }
  __syncthreads();

  const int np = cnt[0], nn = cnt[1];

  float dk[4];
#pragma unroll
  for (int e = 0; e < 4; ++e) {
    int k = tid + 256 * e;
    dk[e] = (k < nn) ? dneg[k] : 1e30f;   // pad -> relu term 0
  }

  float accv = 0.f;
  for (int p = 0; p < np; ++p) {
    float tpos = dpos[p];                 // broadcast LDS read
#pragma unroll
    for (int e = 0; e < 4; ++e) {
      float v = tpos - dk[e];
      accv += (v > 0.f) ? v : 0.f;
    }
  }

  for (int off = 32; off > 0; off >>= 1) accv += __shfl_down(accv, off, 64);
  if (lane == 0) red[tid >> 6] = accv;
  __syncthreads();

  if (tid == 0) {
    partial[i] = red[0] + red[1] + red[2] + red[3];
    __threadfence();                        // release: partial visible device-wide
    isLastS = (atomicAdd(counter, 1) == gridDim.x - 1);
  }
  __syncthreads();
  if (!isLastS) return;

  // last block: deterministic final reduction (fixed order, any winner)
  __threadfence();                          // acquire
  float acc = 0.f;
  for (int j = tid; j < N; j += 256) acc += partial[j];
  for (int off = 32; off > 0; off >>= 1) acc += __shfl_down(acc, off, 64);
  if (lane == 0) red[tid >> 6] = acc;
  __syncthreads();
  if (tid == 0) {
    double s = (double)red[0] + (double)red[1] + (double)red[2] + (double)red[3];
    out[0] = (float)(s / ((double)N + 1e-8));
  }
}

extern "C" void kernel_launch(void* const* d_in, const int* in_sizes, int n_in,
                              void* d_out, int out_size, void* d_ws, size_t ws_size,
                              hipStream_t stream) {
  const float* f = (const float*)d_in[0];
  const int* labels = (const int*)d_in[1];
  int N = in_sizes[1];           // 1024
  int D = in_sizes[0] / N;       // 512
  float* out = (float*)d_out;

  // ws layout: fhi [N*D u16 chunked] | flo [N*D u16 chunked] | sq [N f32]
  //          | dist [N*N f32] | partial [N f32] | counter [1 i32]
  unsigned short* fhi = (unsigned short*)d_ws;
  unsigned short* flo = fhi + (size_t)N * D;
  float* sq = (float*)(flo + (size_t)N * D);
  float* dist = sq + N;
  float* partial = dist + (size_t)N * N;
  int* counter = (int*)(partial + N);

  conv_kernel<<<N, 64, 0, stream>>>(f, fhi, flo, sq, counter, N, D);
  dim3 grid(N / 64, N / 64);
  dist_kernel<<<grid, 256, 0, stream>>>(fhi, flo, sq, dist, N, D);
  anchor_loss_kernel<<<N, 256, 0, stream>>>(dist, labels, counter, out, partial, N);
}

// Round 3
// 79.651 us; speedup vs baseline: 1.2479x; 1.2120x over previous
//
#include <hip/hip_runtime.h>
#include <math.h>

#define MARGIN 1.0f

typedef short short8 __attribute__((ext_vector_type(8)));
typedef unsigned short ushort8 __attribute__((ext_vector_type(8)));
typedef float floatx16 __attribute__((ext_vector_type(16)));

typedef const __attribute__((address_space(1))) void g_void;
typedef __attribute__((address_space(3))) void s_void;

__device__ inline unsigned short bf16_rne(float x) {
  unsigned u = __float_as_uint(x);
  unsigned r = (u + 0x7FFF + ((u >> 16) & 1)) >> 16;
  return (unsigned short)r;
}
__device__ inline float bf16_to_f32(unsigned short h) {
  return __uint_as_float(((unsigned)h) << 16);
}

// ---------------- Kernel A: fp32 -> bf16 hi/lo split (CHUNKED layout) -------
// Round-0 proven structure: 1024 blocks x 64 threads (one wave per row) —
// full-machine parallelism. Chunked layout F_c[kchunk][row][8] makes the
// dist staging fully coalesced; the scattered 16B stores here are absorbed
// by L2/L3 (4 MB total, consumed immediately by dist_kernel).
__global__ __launch_bounds__(64) void conv_kernel(
    const float* __restrict__ f, unsigned short* __restrict__ fhi,
    unsigned short* __restrict__ flo, float* __restrict__ sq, int N, int D) {
  const int r = blockIdx.x;
  const int t = threadIdx.x;
  float acc = 0.f;
  if (t * 8 < D) {
    const float* src = f + (size_t)r * D + t * 8;
    float4 v0 = *(const float4*)(src);
    float4 v1 = *(const float4*)(src + 4);
    float xs[8] = {v0.x, v0.y, v0.z, v0.w, v1.x, v1.y, v1.z, v1.w};
    ushort8 hs, ls;
#pragma unroll
    for (int e = 0; e < 8; ++e) {
      float x = xs[e];
      acc += x * x;
      unsigned short h = bf16_rne(x);
      hs[e] = h;
      ls[e] = bf16_rne(x - bf16_to_f32(h));
    }
    const size_t off = ((size_t)t * N + r) * 8;   // [chunk][row][8]
    *(ushort8*)(fhi + off) = hs;
    *(ushort8*)(flo + off) = ls;
  }
  for (int off = 32; off > 0; off >>= 1) acc += __shfl_down(acc, off, 64);
  if (t == 0) sq[r] = acc;
}

// ---------------- Kernel B: distance matrix via bf16 MFMA hi/lo -------------
// 64x64 tile per block, 4 waves, one 32x32 MFMA tile each. global_load_lds
// staging (16B/lane direct-to-LDS), double-buffered. 3 independent MFMA
// accumulator chains (ah*bh, ah*bl, al*bh) summed in the epilogue -> issue
// ILP at 1 wave/SIMD occupancy (12-deep single chain was latency-exposed).
// NOTE: round-2's fused-final experiment (per-block __threadfence + global
// atomic counter) cost ~18 us — device-scope release = L2 writeback on
// non-coherent XCD L2s + serialized same-address atomics. Do not re-fuse.
__global__ __launch_bounds__(256) void dist_kernel(
    const unsigned short* __restrict__ fhi, const unsigned short* __restrict__ flo,
    const float* __restrict__ sqv, float* __restrict__ dist, int N, int D) {
  // [2 bufs][4 arrays: Ah,Al,Bh,Bl][8 chunks][64 rows] of ushort8 = 64 KB
  __shared__ ushort8 T[2][4][8][64];

  const int tid = threadIdx.x;
  const int w = tid >> 6;          // wave 0..3
  const int lane = tid & 63;
  const int rowBase = blockIdx.y * 64;
  const int colBase = blockIdx.x * 64;

  const unsigned short* srcs[4] = {fhi, flo, fhi, flo};
  const int bases[4] = {rowBase, rowBase, colBase, colBase};

  const int wr = (w >> 1) * 32;
  const int wc = (w & 1) * 32;
  const int m = lane & 31;
  const int h = lane >> 5;         // k-half selector

  auto issueLoads = [&](int k0, int bb) {
    const int c0 = k0 >> 3;
#pragma unroll
    for (int s = 0; s < 8; ++s) {
      const int a = s >> 1;
      const int c = (w << 1) | (s & 1);
      const unsigned short* gp =
          srcs[a] + ((size_t)(c0 + c) * N + bases[a] + lane) * 8;
      __builtin_amdgcn_global_load_lds((g_void*)gp, (s_void*)&T[bb][a][c][0],
                                       16, 0, 0);
    }
  };

  floatx16 acc0 = {}, acc1 = {}, acc2 = {};
  int b = 0;

  issueLoads(0, 0);
  __syncthreads();   // vmcnt(0) drained -> buf0 visible

  for (int k0 = 0; k0 < D; k0 += 64) {
    if (k0 + 64 < D) issueLoads(k0 + 64, b ^ 1);   // async into other buffer
#pragma unroll
    for (int kk = 0; kk < 4; ++kk) {
      const int c = 2 * kk + h;
      short8 ahf = *(const short8*)&T[b][0][c][wr + m];
      short8 alf = *(const short8*)&T[b][1][c][wr + m];
      short8 bhf = *(const short8*)&T[b][2][c][wc + m];
      short8 blf = *(const short8*)&T[b][3][c][wc + m];
      acc0 = __builtin_amdgcn_mfma_f32_32x32x16_bf16(ahf, bhf, acc0, 0, 0, 0);
      acc1 = __builtin_amdgcn_mfma_f32_32x32x16_bf16(ahf, blf, acc1, 0, 0, 0);
      acc2 = __builtin_amdgcn_mfma_f32_32x32x16_bf16(alf, bhf, acc2, 0, 0, 0);
    }
    __syncthreads();   // drains prefetch DMA + all waves' LDS reads of buf b
    b ^= 1;
  }

  // Epilogue: C/D layout col=lane&31, row=(reg&3)+8*(reg>>2)+4*(lane>>5)
  const int col = colBase + wc + m;
  const float sqc = sqv[col];
#pragma unroll
  for (int r = 0; r < 16; ++r) {
    const int row = rowBase + wr + (r & 3) + 8 * (r >> 2) + 4 * h;
    float a = acc0[r] + acc1[r] + acc2[r];
    float d2 = sqv[row] + sqc - 2.0f * a;
    d2 = d2 > 0.f ? d2 : 0.f;
    dist[(size_t)row * N + col] = sqrtf(d2);
  }
}

// ---------------- Kernel C: per-anchor triplet loss (ballot compaction) ----
__global__ __launch_bounds__(256) void anchor_loss_kernel(
    const float* __restrict__ dist, const int* __restrict__ labels,
    float* __restrict__ partial, int N) {
  const int i = blockIdx.x;
  const int tid = threadIdx.x;
  const int lane = tid & 63;

  __shared__ float dpos[1024];   // stored as d + MARGIN
  __shared__ float dneg[1024];
  __shared__ int cnt[2];
  __shared__ float red[4];

  if (tid < 2) cnt[tid] = 0;
  __syncthreads();

  const int lab = labels[i];
  const float* drow = dist + (size_t)i * N;

  for (int jb = 0; jb < N; jb += 256) {
    int j = jb + tid;
    float d = drow[j];
    bool isPos = (labels[j] == lab);

    unsigned long long mp = __ballot(isPos);
    unsigned long long mn = ~mp;   // all 64 lanes valid (N % 256 == 0)
    unsigned long long lt = (1ull << lane) - 1ull;

    int base_p = 0, base_n = 0;
    if (lane == 0) {
      base_p = atomicAdd(&cnt[0], __popcll(mp));
      base_n = atomicAdd(&cnt[1], 64 - __popcll(mp));
    }
    base_p = __shfl(base_p, 0, 64);
    base_n = __shfl(base_n, 0, 64);

    if (isPos) dpos[base_p + __popcll(mp & lt)] = d + MARGIN;
    else       dneg[base_n + __popcll(mn & lt)] = d;
  }
  __syncthreads();

  const int np = cnt[0], nn = cnt[1];

  float dk[4];
#pragma unroll
  for (int e = 0; e < 4; ++e) {
    int k = tid + 256 * e;
    dk[e] = (k < nn) ? dneg[k] : 1e30f;   // pad -> relu term 0
  }

  float accv = 0.f;
  for (int p = 0; p < np; ++p) {
    float t = dpos[p];                    // broadcast LDS read
#pragma unroll
    for (int e = 0; e < 4; ++e) {
      float v = t - dk[e];
      accv += (v > 0.f) ? v : 0.f;
    }
  }

  for (int off = 32; off > 0; off >>= 1) accv += __shfl_down(accv, off, 64);
  if (lane == 0) red[tid >> 6] = accv;
  __syncthreads();
  if (tid == 0) partial[i] = red[0] + red[1] + red[2] + red[3];
}

// ---------------- Kernel D: final reduction ----------------
__global__ __launch_bounds__(256) void final_reduce_kernel(
    const float* __restrict__ partial, float* __restrict__ out, int N) {
  float acc = 0.f;
  for (int j = threadIdx.x; j < N; j += 256) acc += partial[j];
  for (int off = 32; off > 0; off >>= 1) acc += __shfl_down(acc, off, 64);
  __shared__ float red[4];
  if ((threadIdx.x & 63) == 0) red[threadIdx.x >> 6] = acc;
  __syncthreads();
  if (threadIdx.x == 0) {
    double s = (double)red[0] + (double)red[1] + (double)red[2] + (double)red[3];
    out[0] = (float)(s / ((double)N + 1e-8));
  }
}

extern "C" void kernel_launch(void* const* d_in, const int* in_sizes, int n_in,
                              void* d_out, int out_size, void* d_ws, size_t ws_size,
                              hipStream_t stream) {
  const float* f = (const float*)d_in[0];
  const int* labels = (const int*)d_in[1];
  int N = in_sizes[1];           // 1024
  int D = in_sizes[0] / N;       // 512
  float* out = (float*)d_out;

  // ws layout: fhi [N*D u16 chunked] | flo [N*D u16 chunked] | sq [N f32]
  //          | dist [N*N f32] | partial [N f32]
  unsigned short* fhi = (unsigned short*)d_ws;
  unsigned short* flo = fhi + (size_t)N * D;
  float* sq = (float*)(flo + (size_t)N * D);
  float* dist = sq + N;
  float* partial = dist + (size_t)N * N;

  conv_kernel<<<N, 64, 0, stream>>>(f, fhi, flo, sq, N, D);
  dim3 grid(N / 64, N / 64);
  dist_kernel<<<grid, 256, 0, stream>>>(fhi, flo, sq, dist, N, D);
  anchor_loss_kernel<<<N, 256, 0, stream>>>(dist, labels, partial, N);
  final_reduce_kernel<<<1, 256, 0, stream>>>(partial, out, N);
}